// Round 12
// baseline (181.574 us; speedup 1.0000x reference)
//
#include <hip/hip_runtime.h>

typedef unsigned short u16;
typedef __attribute__((ext_vector_type(8))) short bf16x8;
typedef __attribute__((ext_vector_type(4))) float f32x4;

#define Bb 2
#define Tt 2048
#define Dd 1024
#define Hh 16
#define HD 64
#define NTOK (Bb*Tt)   // 4096
#define QKVN (3*Dd)    // 3072

__device__ __forceinline__ u16 f2b(float f) {
    unsigned u = __float_as_uint(f);
    unsigned r = (u + 0x7fffu + ((u >> 16) & 1u)) >> 16;
    return (u16)r;
}

// async global->LDS, 16B per lane; LDS dest = wave-uniform base + lane*16
__device__ __forceinline__ void g2l16(const u16* g, u16* l) {
    __builtin_amdgcn_global_load_lds(
        (const __attribute__((address_space(1))) unsigned int*)g,
        (__attribute__((address_space(3))) unsigned int*)l,
        16, 0, 0);
}

// pack two fp32 -> two bf16 (truncate) in one v_perm
__device__ __forceinline__ unsigned pk2(float lo, float hi) {
    return __builtin_amdgcn_perm(__float_as_uint(hi), __float_as_uint(lo), 0x07060302u);
}

// ---------------- fused fp32 -> bf16 convert ----------------
#define N4X  (NTOK * Dd / 4)
#define N4WQ (3 * Dd * Dd / 4)
#define N4WP (Dd * Dd / 4)
__global__ void cvt_all(const float* __restrict__ x, const float* __restrict__ wq,
                        const float* __restrict__ wp, u16* __restrict__ xb,
                        u16* __restrict__ wqb, u16* __restrict__ wpb) {
    int i = blockIdx.x * blockDim.x + threadIdx.x;
    const float* src; u16* dst; int j;
    if (i < N4X)                { src = x;  dst = xb;  j = i; }
    else if (i < N4X + N4WQ)    { src = wq; dst = wqb; j = i - N4X; }
    else                        { src = wp; dst = wpb; j = i - N4X - N4WQ; }
    float4 f = ((const float4*)src)[j];
    ushort4 o;
    o.x = f2b(f.x); o.y = f2b(f.y); o.z = f2b(f.z); o.w = f2b(f.w);
    ((ushort4*)dst)[j] = o;
}

// ---------------- GEMM1: qkv = x @ Wqkv^T + b. 128x128 tile, BK=64 ----
#define TRS 136   // transpose LDS stride (u16)

__global__ __launch_bounds__(256, 3)
void gemm_qkv(const u16* __restrict__ A, const u16* __restrict__ Bt,
              const float* __restrict__ bias,
              u16* __restrict__ C16, u16* __restrict__ Vt) {
    const int N = QKVN, K = Dd;
    __shared__ alignas(16) u16 smem[128 * TRS];
    u16* As = smem;
    u16* Bs = smem + 8192;
    const int tid = threadIdx.x;
    const int wave = tid >> 6, lane = tid & 63;
    const int quad = lane >> 4, l16 = lane & 15;
    const int wm = (wave & 1) * 64, wn = (wave >> 1) * 64;
    const int m0 = blockIdx.x * 128, n0 = blockIdx.y * 128;
    const int lrow = lane >> 2, lcol = (lane & 3) << 3;

    f32x4 acc[4][4];
#pragma unroll
    for (int i = 0; i < 4; ++i)
#pragma unroll
        for (int j = 0; j < 4; ++j)
            acc[i][j] = (f32x4){0.f, 0.f, 0.f, 0.f};

    for (int k0 = 0; k0 < K; k0 += 64) {
#pragma unroll
        for (int h = 0; h < 2; ++h)
#pragma unroll
            for (int c = 0; c < 2; ++c) {
                const int rb = (c * 4 + wave) * 16;
                g2l16(A  + (size_t)(m0 + rb + lrow) * K + k0 + h * 32 + lcol,
                      &As[h * 4096 + rb * 32 + (lane << 3)]);
                g2l16(Bt + (size_t)(n0 + rb + lrow) * K + k0 + h * 32 + lcol,
                      &Bs[h * 4096 + rb * 32 + (lane << 3)]);
            }
        __syncthreads();
        bf16x8 a[4][2], b[4][2];
#pragma unroll
        for (int h = 0; h < 2; ++h) {
#pragma unroll
            for (int i = 0; i < 4; ++i)
                a[i][h] = *(const bf16x8*)(&As[h * 4096 + (wm + i * 16 + l16) * 32 + quad * 8]);
#pragma unroll
            for (int i = 0; i < 4; ++i)
                b[i][h] = *(const bf16x8*)(&Bs[h * 4096 + (wn + i * 16 + l16) * 32 + quad * 8]);
        }
#pragma unroll
        for (int h = 0; h < 2; ++h)
#pragma unroll
            for (int i = 0; i < 4; ++i)
#pragma unroll
                for (int j = 0; j < 4; ++j)
                    acc[i][j] = __builtin_amdgcn_mfma_f32_16x16x32_bf16(a[i][h], b[j][h], acc[i][j], 0, 0, 0);
        __syncthreads();
    }

    float b4[4];
#pragma unroll
    for (int j = 0; j < 4; ++j) b4[j] = bias[n0 + wn + j * 16 + l16];
    const bool isV = (n0 >= 2 * Dd);   // block-uniform

    if (!isV) {
#pragma unroll
        for (int i = 0; i < 4; ++i)
#pragma unroll
            for (int j = 0; j < 4; ++j)
#pragma unroll
                for (int r = 0; r < 4; ++r) {
                    int m = m0 + wm + i * 16 + quad * 4 + r;
                    int n = n0 + wn + j * 16 + l16;
                    C16[(size_t)m * N + n] = f2b(acc[i][j][r] + b4[j]);
                }
    } else {
#pragma unroll
        for (int i = 0; i < 4; ++i)
#pragma unroll
            for (int j = 0; j < 4; ++j)
#pragma unroll
                for (int r = 0; r < 4; ++r) {
                    int ml = wm + i * 16 + quad * 4 + r;
                    int nl = wn + j * 16 + l16;
                    smem[nl * TRS + ml] = f2b(acc[i][j][r] + b4[j]);
                }
        __syncthreads();
        const int bidx = m0 >> 11, t0 = m0 & 2047;
        const int nl = tid >> 1, toff = (tid & 1) * 64;
        u16* dst = Vt + (size_t)bidx * (Hh * HD * Tt)
                      + (size_t)(n0 - 2 * Dd + nl) * Tt + t0 + toff;
        const u16* srcl = &smem[nl * TRS + toff];
#pragma unroll
        for (int k = 0; k < 8; ++k)
            *(uint4*)(dst + k * 8) = *(const uint4*)(srcl + k * 8);
    }
}

// ---------------- GEMM2: out = attn @ Wproj^T + b. 128x64 tiles, BK=64, fp32 out ----------------
__global__ __launch_bounds__(256, 2)
void gemm_proj(const u16* __restrict__ A, const u16* __restrict__ Bt,
               const float* __restrict__ bias, float* __restrict__ Co) {
    const int N = Dd, K = Dd;
    __shared__ alignas(16) u16 As[2 * 128 * 32];
    __shared__ alignas(16) u16 Bs[2 * 64 * 32];
    const int tid = threadIdx.x;
    const int wave = tid >> 6, lane = tid & 63;
    const int quad = lane >> 4, l16 = lane & 15;
    const int wm = (wave & 1) * 64, wn = (wave >> 1) * 32;
    const int m0 = blockIdx.x * 128, n0 = blockIdx.y * 64;
    const int lrow = lane >> 2, lcol = (lane & 3) << 3;

    f32x4 acc[4][2];
#pragma unroll
    for (int i = 0; i < 4; ++i)
#pragma unroll
        for (int j = 0; j < 2; ++j)
            acc[i][j] = (f32x4){0.f, 0.f, 0.f, 0.f};

    for (int k0 = 0; k0 < K; k0 += 64) {
#pragma unroll
        for (int h = 0; h < 2; ++h) {
#pragma unroll
            for (int c = 0; c < 2; ++c) {
                const int rb = (c * 4 + wave) * 16;
                g2l16(A + (size_t)(m0 + rb + lrow) * K + k0 + h * 32 + lcol,
                      &As[h * 4096 + rb * 32 + (lane << 3)]);
            }
            g2l16(Bt + (size_t)(n0 + wave * 16 + lrow) * K + k0 + h * 32 + lcol,
                  &Bs[h * 2048 + (wave * 16) * 32 + (lane << 3)]);
        }
        __syncthreads();
        bf16x8 a[4][2], b[2][2];
#pragma unroll
        for (int h = 0; h < 2; ++h) {
#pragma unroll
            for (int i = 0; i < 4; ++i)
                a[i][h] = *(const bf16x8*)(&As[h * 4096 + (wm + i * 16 + l16) * 32 + quad * 8]);
#pragma unroll
            for (int j = 0; j < 2; ++j)
                b[j][h] = *(const bf16x8*)(&Bs[h * 2048 + (wn + j * 16 + l16) * 32 + quad * 8]);
        }
#pragma unroll
        for (int h = 0; h < 2; ++h)
#pragma unroll
            for (int i = 0; i < 4; ++i)
#pragma unroll
                for (int j = 0; j < 2; ++j)
                    acc[i][j] = __builtin_amdgcn_mfma_f32_16x16x32_bf16(a[i][h], b[j][h], acc[i][j], 0, 0, 0);
        __syncthreads();
    }

    float b2[2];
#pragma unroll
    for (int j = 0; j < 2; ++j) b2[j] = bias[n0 + wn + j * 16 + l16];

#pragma unroll
    for (int i = 0; i < 4; ++i)
#pragma unroll
        for (int j = 0; j < 2; ++j)
#pragma unroll
            for (int r = 0; r < 4; ++r) {
                int m = m0 + wm + i * 16 + quad * 4 + r;
                int n = n0 + wn + j * 16 + l16;
                Co[(size_t)m * N + n] = acc[i][j][r] + b2[j];
            }
}

// ---------------- flash attention: COMBINED paired pass ----------------
// Light tile (qtL=p) rides the heavy tile's (qtH=31-p) staged K/V: its key range is a
// prefix, so one staging pass serves both. ak/av fragments loaded once, used by both
// tiles' MFMAs. Phases keep all branches block-uniform; diag masks via per-lane mb.
// p remapped so co-resident blocks (y, y+16) get complementary p: per-CU staging uniform.
#define LKP 80
#define PSP 84
#define FMX 24.0f

#define MFMA16(a,b,c) __builtin_amdgcn_mfma_f32_16x16x32_bf16(a, b, c, 0, 0, 0)

template<bool LIGHT, bool MASKH, bool MASKL>
__device__ __forceinline__ void attn_iter(
    const u16* Kcur, const u16* Vcur, u16* PwH, u16* PwL,
    const bf16x8 (&aqH)[2], const bf16x8 (&aqL)[2],
    f32x4 (&oH)[4], f32x4 (&oL)[4], float& lsH, float& lsL,
    const float (&mb)[16], int l16, int quad, float sc)
{
    f32x4 sH[4], sL[4];
#pragma unroll
    for (int nt = 0; nt < 4; ++nt) {
        f32x4 zH = (f32x4){0.f, 0.f, 0.f, 0.f};
        f32x4 zL = (f32x4){0.f, 0.f, 0.f, 0.f};
#pragma unroll
        for (int kk = 0; kk < 2; ++kk) {
            bf16x8 ak = *(const bf16x8*)(&Kcur[(nt * 16 + l16) * LKP + kk * 32 + quad * 8]);
            zH = MFMA16(ak, aqH[kk], zH);
            if (LIGHT) zL = MFMA16(ak, aqL[kk], zL);
        }
        sH[nt] = zH;
        if (LIGHT) sL[nt] = zL;
    }
#pragma unroll
    for (int nt = 0; nt < 4; ++nt)
#pragma unroll
        for (int r = 0; r < 4; ++r) {
            float pH = exp2f(__builtin_fmaf(sH[nt][r], sc, MASKH ? mb[nt * 4 + r] : -FMX));
            sH[nt][r] = pH; lsH += pH;
            if (LIGHT) {
                float pL = exp2f(__builtin_fmaf(sL[nt][r], sc, MASKL ? mb[nt * 4 + r] : -FMX));
                sL[nt][r] = pL; lsL += pL;
            }
        }
#pragma unroll
    for (int nt = 0; nt < 4; ++nt) {
        uint2 d;
        d.x = pk2(sH[nt][0], sH[nt][1]); d.y = pk2(sH[nt][2], sH[nt][3]);
        *(uint2*)(&PwH[l16 * PSP + nt * 16 + quad * 4]) = d;
        if (LIGHT) {
            uint2 e;
            e.x = pk2(sL[nt][0], sL[nt][1]); e.y = pk2(sL[nt][2], sL[nt][3]);
            *(uint2*)(&PwL[l16 * PSP + nt * 16 + quad * 4]) = e;
        }
    }
#pragma unroll
    for (int kk = 0; kk < 2; ++kk) {
        bf16x8 bpH = *(const bf16x8*)(&PwH[l16 * PSP + kk * 32 + quad * 8]);
        bf16x8 bpL;
        if (LIGHT) bpL = *(const bf16x8*)(&PwL[l16 * PSP + kk * 32 + quad * 8]);
#pragma unroll
        for (int nt = 0; nt < 4; ++nt) {
            bf16x8 av = *(const bf16x8*)(&Vcur[(nt * 16 + l16) * LKP + kk * 32 + quad * 8]);
            oH[nt] = MFMA16(av, bpH, oH[nt]);
            if (LIGHT) oL[nt] = MFMA16(av, bpL, oL[nt]);
        }
    }
}

__global__ __launch_bounds__(256, 2)
void attn_fwd(const u16* __restrict__ qkv, const u16* __restrict__ Vt,
              u16* __restrict__ Ao) {
    // complementary-p remap: blocks (x,y) and (x,y+16) likely co-resident -> give them
    // p = x and 15-x so per-CU staging totals are uniform (49 tiles).
    const int p = ((int)blockIdx.y < 16) ? (int)blockIdx.x : 15 - (int)blockIdx.x;
    const int qtH = 31 - p, qtL = p;
    const int bh = blockIdx.y;
    const int hh = bh & (Hh - 1), bidx = bh >> 4;
    const u16* Qp = qkv + (size_t)bidx * Tt * QKVN + hh * HD;
    const u16* Kp = Qp + Dd;
    const u16* Vp = Vt + (size_t)bh * HD * Tt;
    const int tid = threadIdx.x;
    const int wave = tid >> 6, lane = tid & 63;
    const int quad = lane >> 4, l16 = lane & 15;

    __shared__ alignas(16) u16 Ks[2][64 * LKP];
    __shared__ alignas(16) u16 Vs[2][64 * LKP];
    __shared__ alignas(16) u16 Ps[4][2][16 * PSP];
    u16* PwH = &Ps[wave][0][0];
    u16* PwL = &Ps[wave][1][0];

    const int srow = tid >> 3, scol = (tid & 7) << 3;
    const int st0 = srow * LKP + scol, st1 = (srow + 32) * LKP + scol;
    const float sc = 0.125f * 1.44269504f;

    float mb[16];
#pragma unroll
    for (int nt = 0; nt < 4; ++nt)
#pragma unroll
        for (int r = 0; r < 4; ++r)
            mb[nt * 4 + r] = (nt * 16 + quad * 4 + r <= wave * 16 + l16) ? -FMX : -250.0f;

    const int qrowH = qtH * 64 + wave * 16 + l16;
    const int qrowL = qtL * 64 + wave * 16 + l16;
    bf16x8 aqH[2], aqL[2];
#pragma unroll
    for (int kk = 0; kk < 2; ++kk) {
        aqH[kk] = *(const bf16x8*)(Qp + (size_t)qrowH * QKVN + kk * 32 + quad * 8);
        aqL[kk] = *(const bf16x8*)(Qp + (size_t)qrowL * QKVN + kk * 32 + quad * 8);
    }

    f32x4 oH[4], oL[4];
#pragma unroll
    for (int nt = 0; nt < 4; ++nt) {
        oH[nt] = (f32x4){0.f, 0.f, 0.f, 0.f};
        oL[nt] = (f32x4){0.f, 0.f, 0.f, 0.f};
    }
    float lsH = 0.f, lsL = 0.f;

    // preload tile 0 into buffer 0
    {
        uint4 k0r = *(const uint4*)(Kp + (size_t)srow * QKVN + scol);
        uint4 k1r = *(const uint4*)(Kp + (size_t)(srow + 32) * QKVN + scol);
        uint4 v0r = *(const uint4*)(Vp + (size_t)srow * Tt + scol);
        uint4 v1r = *(const uint4*)(Vp + (size_t)(srow + 32) * Tt + scol);
        *(uint4*)(&Ks[0][st0]) = k0r;
        *(uint4*)(&Ks[0][st1]) = k1r;
        *(uint4*)(&Vs[0][st0]) = v0r;
        *(uint4*)(&Vs[0][st1]) = v1r;
    }
    __syncthreads();

    const u16* kp0 = Kp + (size_t)(64 + srow) * QKVN + scol;
    const u16* kp1 = kp0 + (size_t)32 * QKVN;
    const u16* vp0 = Vp + (size_t)srow * Tt + 64 + scol;
    const u16* vp1 = vp0 + (size_t)32 * Tt;
    u16* Kcur = &Ks[0][0]; u16* Knxt = &Ks[1][0];
    u16* Vcur = &Vs[0][0]; u16* Vnxt = &Vs[1][0];

#define PREFETCH \
    uint4 k0r = *(const uint4*)kp0, k1r = *(const uint4*)kp1; \
    uint4 v0r = *(const uint4*)vp0, v1r = *(const uint4*)vp1; \
    kp0 += (size_t)64 * QKVN; kp1 += (size_t)64 * QKVN; vp0 += 64; vp1 += 64;

#define STAGE_SWAP \
    *(uint4*)(&Knxt[st0]) = k0r; *(uint4*)(&Knxt[st1]) = k1r; \
    *(uint4*)(&Vnxt[st0]) = v0r; *(uint4*)(&Vnxt[st1]) = v1r; \
    { u16* t = Kcur; Kcur = Knxt; Knxt = t; t = Vcur; Vcur = Vnxt; Vnxt = t; } \
    __syncthreads();

    // phase 1: kt < qtL — both tiles, no masks. (prefetch kt+1 <= qtH always valid)
    for (int kt = 0; kt < qtL; ++kt) {
        PREFETCH
        attn_iter<true, false, false>(Kcur, Vcur, PwH, PwL, aqH, aqL, oH, oL, lsH, lsL, mb, l16, quad, sc);
        STAGE_SWAP
    }
    // phase 2: kt == qtL — light diagonal (qtL < qtH so prefetch still valid)
    {
        PREFETCH
        attn_iter<true, false, true>(Kcur, Vcur, PwH, PwL, aqH, aqL, oH, oL, lsH, lsL, mb, l16, quad, sc);
        STAGE_SWAP
    }
    // phase 3: qtL < kt < qtH — heavy only
    for (int kt = qtL + 1; kt < qtH; ++kt) {
        PREFETCH
        attn_iter<false, false, false>(Kcur, Vcur, PwH, PwL, aqH, aqL, oH, oL, lsH, lsL, mb, l16, quad, sc);
        STAGE_SWAP
    }
    // phase 4: kt == qtH — heavy diagonal, no prefetch, no trailing barrier
    attn_iter<false, true, false>(Kcur, Vcur, PwH, PwL, aqH, aqL, oH, oL, lsH, lsL, mb, l16, quad, sc);

    // epilogues
    lsH += __shfl_xor(lsH, 16, 64);
    lsH += __shfl_xor(lsH, 32, 64);
    lsL += __shfl_xor(lsL, 16, 64);
    lsL += __shfl_xor(lsL, 32, 64);
    const float rH = 1.0f / lsH, rL = 1.0f / lsL;
    u16* orowH = Ao + ((size_t)bidx * Tt + qrowH) * Dd + hh * HD;
    u16* orowL = Ao + ((size_t)bidx * Tt + qrowL) * Dd + hh * HD;
#pragma unroll
    for (int nt = 0; nt < 4; ++nt) {
        ushort4 pH, pL;
        pH.x = f2b(oH[nt][0] * rH); pH.y = f2b(oH[nt][1] * rH);
        pH.z = f2b(oH[nt][2] * rH); pH.w = f2b(oH[nt][3] * rH);
        *(ushort4*)(orowH + nt * 16 + quad * 4) = pH;
        pL.x = f2b(oL[nt][0] * rL); pL.y = f2b(oL[nt][1] * rL);
        pL.z = f2b(oL[nt][2] * rL); pL.w = f2b(oL[nt][3] * rL);
        *(ushort4*)(orowL + nt * 16 + quad * 4) = pL;
    }
}

extern "C" void kernel_launch(void* const* d_in, const int* in_sizes, int n_in,
                              void* d_out, int out_size, void* d_ws, size_t ws_size,
                              hipStream_t stream) {
    const float* x      = (const float*)d_in[0];
    const float* W_qkv  = (const float*)d_in[1];
    const float* b_qkv  = (const float*)d_in[2];
    const float* W_proj = (const float*)d_in[3];
    const float* b_proj = (const float*)d_in[4];
    float* out = (float*)d_out;

    // 48 MiB layout:
    //   [0,2)    Wprojb   (live until gemm2)
    //   [2,8)    Wqkvb    (dead after gemm1)  \__ attnb aliases [2,10)
    //   [8,16)   xb       (dead after gemm1)  /
    //   [16,40)  qkvb     (dead after attn)
    //   [40,48)  Vtb      (dead after attn)
    char* ws = (char*)d_ws;
    u16* Wprojb = (u16*)(ws);
    u16* Wqkvb  = (u16*)(ws + (2u << 20));
    u16* xb     = (u16*)(ws + (8u << 20));
    u16* qkvb   = (u16*)(ws + (16u << 20));
    u16* Vtb    = (u16*)(ws + (40u << 20));
    u16* attnb  = (u16*)(ws + (2u << 20));   // aliases Wqkvb+xb (dead by then)

    cvt_all<<<(N4X + N4WQ + N4WP) / 256, 256, 0, stream>>>(x, W_qkv, W_proj, xb, Wqkvb, Wprojb);

    {
        dim3 grid(NTOK / 128, QKVN / 128);   // 32 x 24 = 768 blocks
        gemm_qkv<<<grid, 256, 0, stream>>>(xb, Wqkvb, b_qkv, qkvb, Vtb);
    }
    {
        dim3 grid(16, Bb * Hh);   // 16 combined pairs x 32 bh
        attn_fwd<<<grid, 256, 0, stream>>>(qkvb, Vtb, attnb);
    }
    {
        dim3 grid(NTOK / 128, Dd / 64);   // 32 x 16 = 512 blocks
        gemm_proj<<<grid, 256, 0, stream>>>(attnb, Wprojb, b_proj, out);
    }
}